// Round 1
// baseline (747.065 us; speedup 1.0000x reference)
//
#include <hip/hip_runtime.h>

#define FD 128

// ---------- edge-index dtype normalization ----------
// If the (2,E) edge_index arrived as int64, every element's high 32-bit word
// is 0 (values in [0,50000)). If int32, "odd words" are real random indices.
__global__ void detect_k(const unsigned int* __restrict__ ei, int* __restrict__ flag, int nelem) {
    __shared__ int any;
    if (threadIdx.x == 0) any = 0;
    __syncthreads();
    int samples = 2048;
    if (samples > nelem) samples = nelem;
    for (int i = threadIdx.x; i < samples; i += blockDim.x) {
        if (ei[2 * i + 1] != 0u) any = 1;   // benign race
    }
    __syncthreads();
    if (threadIdx.x == 0) *flag = any;      // any!=0  -> data is int32
}

__global__ void convert_k(const int* __restrict__ ei32, const long long* __restrict__ ei64,
                          const int* __restrict__ flag, int* __restrict__ s32,
                          int* __restrict__ d32, int E) {
    int e = blockIdx.x * blockDim.x + threadIdx.x;
    if (e >= E) return;
    if (*flag) {                 // int32 source
        s32[e] = ei32[e];
        d32[e] = ei32[E + e];
    } else {                     // int64 source, narrow
        s32[e] = (int)ei64[e];
        d32[e] = (int)ei64[E + e];
    }
}

// ---------- CSR build ----------
__global__ void count_k(const int* __restrict__ dst, int* __restrict__ cnt, int E) {
    int e = blockIdx.x * blockDim.x + threadIdx.x;
    if (e < E) atomicAdd(&cnt[dst[e]], 1);
}

// single-block exclusive scan (Hillis-Steele chunks of 1024)
__global__ void exscan_k(const int* __restrict__ cnt, int* __restrict__ rp, int n) {
    __shared__ int tmp[1024];
    __shared__ int carry;
    if (threadIdx.x == 0) { carry = 0; rp[0] = 0; }
    __syncthreads();
    for (int base = 0; base < n; base += 1024) {
        int i = base + (int)threadIdx.x;
        int v = (i < n) ? cnt[i] : 0;
        tmp[threadIdx.x] = v;
        __syncthreads();
        for (int off = 1; off < 1024; off <<= 1) {
            int add = (threadIdx.x >= (unsigned)off) ? tmp[threadIdx.x - off] : 0;
            __syncthreads();
            tmp[threadIdx.x] += add;
            __syncthreads();
        }
        int c = carry;
        if (i < n) rp[i + 1] = c + tmp[threadIdx.x];
        __syncthreads();
        if (threadIdx.x == 0) carry = c + tmp[1023];
        __syncthreads();
    }
}

__global__ void fill_k(const int* __restrict__ src, const int* __restrict__ dst,
                       const int* __restrict__ rp, int* __restrict__ cursor,
                       int* __restrict__ srcs, int E) {
    int e = blockIdx.x * blockDim.x + threadIdx.x;
    if (e < E) {
        int d = dst[e];
        int p = atomicAdd(&cursor[d], 1);
        srcs[rp[d] + p] = src[e];
    }
}

// ---------- per-layer kernels ----------
// one block (128 threads) per destination node; thread = feature column
__global__ void agg_k(const float* __restrict__ x, const int* __restrict__ rp,
                      const int* __restrict__ srcs, float* __restrict__ agg) {
    int n = blockIdx.x;
    int t = threadIdx.x;
    int e0 = rp[n], e1 = rp[n + 1];
    float acc = 0.f;
    for (int e = e0; e < e1; ++e) {
        int s = srcs[e];
        acc += x[(size_t)s * FD + t];
    }
    agg[(size_t)n * FD + t] = acc;
}

// out[n][h] = sum_d Wrel[h][d]*agg[n][d] + bias[h] + sum_d Wroot[h][d]*x[n][d]
// 16 nodes per block; 256 threads: h = t&127, which half of nodes = t>>7.
__global__ __launch_bounds__(256) void gemm_k(
        const float* __restrict__ aggM, const float* __restrict__ xin,
        const float* __restrict__ Wrel, const float* __restrict__ Wroot,
        const float* __restrict__ bias, float* __restrict__ out, int N, int doRelu) {
    __shared__ float sa[16][FD];
    __shared__ float sx[16][FD];
    int b0 = blockIdx.x * 16;
    for (int i = threadIdx.x; i < 16 * (FD / 4); i += 256) {
        int node = i / (FD / 4);
        int c4 = i % (FD / 4);
        int gn = b0 + node;
        if (gn >= N) gn = N - 1;
        ((float4*)&sa[node][0])[c4] = ((const float4*)(aggM + (size_t)gn * FD))[c4];
        ((float4*)&sx[node][0])[c4] = ((const float4*)(xin + (size_t)gn * FD))[c4];
    }
    __syncthreads();
    int h = threadIdx.x & (FD - 1);
    int which = threadIdx.x >> 7;
    float acc[8];
    float bb = bias[h];
#pragma unroll
    for (int i = 0; i < 8; ++i) acc[i] = bb;
    const float4* wr = (const float4*)(Wrel + (size_t)h * FD);
    const float4* wo = (const float4*)(Wroot + (size_t)h * FD);
#pragma unroll 4
    for (int d4 = 0; d4 < FD / 4; ++d4) {
        float4 a = wr[d4];
        float4 b = wo[d4];
#pragma unroll
        for (int i = 0; i < 8; ++i) {
            int nd = which * 8 + i;
            float4 va = ((const float4*)&sa[nd][0])[d4];
            float4 vx = ((const float4*)&sx[nd][0])[d4];
            acc[i] += a.x * va.x + a.y * va.y + a.z * va.z + a.w * va.w
                    + b.x * vx.x + b.y * vx.y + b.z * vx.z + b.w * vx.w;
        }
    }
#pragma unroll
    for (int i = 0; i < 8; ++i) {
        int nd = which * 8 + i;
        int gn = b0 + nd;
        if (gn < N) {
            float v = acc[i];
            if (doRelu) v = fmaxf(v, 0.f);
            out[(size_t)gn * FD + h] = v;
        }
    }
}

extern "C" void kernel_launch(void* const* d_in, const int* in_sizes, int n_in,
                              void* d_out, int out_size, void* d_ws, size_t ws_size,
                              hipStream_t stream) {
    const float* x   = (const float*)d_in[0];
    const int*   ei32 = (const int*)d_in[1];
    const long long* ei64 = (const long long*)d_in[1];
    const float* W1r = (const float*)d_in[2];
    const float* b1  = (const float*)d_in[3];
    const float* W1o = (const float*)d_in[4];
    const float* W2r = (const float*)d_in[5];
    const float* b2  = (const float*)d_in[6];
    const float* W2o = (const float*)d_in[7];
    const float* W3r = (const float*)d_in[8];
    const float* b3  = (const float*)d_in[9];
    const float* W3o = (const float*)d_in[10];

    int N = in_sizes[0] / FD;
    int E = in_sizes[1] / 2;

    char* ws = (char*)d_ws;
    size_t off = 0;
    auto alloc = [&](size_t bytes) -> void* {
        void* p = ws + off;
        off = (off + bytes + 255) & ~(size_t)255;
        return p;
    };
    int*   flag = (int*)alloc(4);
    int*   rp   = (int*)alloc((size_t)(N + 1) * 4);
    int*   cnt  = (int*)alloc((size_t)N * 4);
    int*   cur  = (int*)alloc((size_t)N * 4);
    int*   s32  = (int*)alloc((size_t)E * 4);
    int*   d32  = (int*)alloc((size_t)E * 4);
    int*   srcs = (int*)alloc((size_t)E * 4);
    float* agg  = (float*)alloc((size_t)N * FD * 4);
    float* h1   = (float*)alloc((size_t)N * FD * 4);
    float* h2   = (float*)alloc((size_t)N * FD * 4);
    (void)ws_size; (void)n_in; (void)out_size;

    hipMemsetAsync(cnt, 0, (size_t)N * 4, stream);
    hipMemsetAsync(cur, 0, (size_t)N * 4, stream);

    detect_k<<<1, 256, 0, stream>>>((const unsigned int*)d_in[1], flag, E);
    convert_k<<<(E + 255) / 256, 256, 0, stream>>>(ei32, ei64, flag, s32, d32, E);
    count_k<<<(E + 255) / 256, 256, 0, stream>>>(d32, cnt, E);
    exscan_k<<<1, 1024, 0, stream>>>(cnt, rp, N);
    fill_k<<<(E + 255) / 256, 256, 0, stream>>>(s32, d32, rp, cur, srcs, E);

    int gblocks = (N + 15) / 16;

    // layer 1
    agg_k<<<N, FD, 0, stream>>>(x, rp, srcs, agg);
    gemm_k<<<gblocks, 256, 0, stream>>>(agg, x, W1r, W1o, b1, h1, N, 1);
    // layer 2
    agg_k<<<N, FD, 0, stream>>>(h1, rp, srcs, agg);
    gemm_k<<<gblocks, 256, 0, stream>>>(agg, h1, W2r, W2o, b2, h2, N, 1);
    // layer 3
    agg_k<<<N, FD, 0, stream>>>(h2, rp, srcs, agg);
    gemm_k<<<gblocks, 256, 0, stream>>>(agg, h2, W3r, W3o, b3, (float*)d_out, N, 0);
}

// Round 2
// 334.962 us; speedup vs baseline: 2.2303x; 2.2303x over previous
//
#include <hip/hip_runtime.h>

#define FD 128
typedef __attribute__((ext_vector_type(8))) short short8;
typedef __attribute__((ext_vector_type(4))) float f32x4;

__device__ __forceinline__ unsigned short f2b(float f) {
    unsigned u = __builtin_bit_cast(unsigned, f);
    unsigned r = (u + 0x7FFFu + ((u >> 16) & 1u)) >> 16;
    return (unsigned short)r;
}
__device__ __forceinline__ float b2f(unsigned short h) {
    unsigned u = ((unsigned)h) << 16;
    return __builtin_bit_cast(float, u);
}

// ---------- edge-index dtype normalization ----------
__global__ void detect_k(const unsigned int* __restrict__ ei, int* __restrict__ flag, int nelem) {
    __shared__ int any;
    if (threadIdx.x == 0) any = 0;
    __syncthreads();
    int samples = 2048;
    if (samples > nelem) samples = nelem;
    for (int i = threadIdx.x; i < samples; i += blockDim.x)
        if (ei[2 * i + 1] != 0u) any = 1;
    __syncthreads();
    if (threadIdx.x == 0) *flag = any;   // any!=0 -> int32 data
}

__global__ void convert_k(const int* __restrict__ ei32, const long long* __restrict__ ei64,
                          const int* __restrict__ flag, int* __restrict__ s32,
                          int* __restrict__ d32, int E) {
    int e = blockIdx.x * blockDim.x + threadIdx.x;
    if (e >= E) return;
    if (*flag) { s32[e] = ei32[e]; d32[e] = ei32[E + e]; }
    else       { s32[e] = (int)ei64[e]; d32[e] = (int)ei64[E + e]; }
}

// ---------- CSR build ----------
__global__ void count_k(const int* __restrict__ dst, int* __restrict__ cnt, int E) {
    int e = blockIdx.x * blockDim.x + threadIdx.x;
    if (e < E) atomicAdd(&cnt[dst[e]], 1);
}

// hierarchical scan: per-block inclusive scan -> scan block sums -> add offsets
__global__ void scan1_k(const int* __restrict__ cnt, int* __restrict__ rp,
                        int* __restrict__ bsum, int n) {
    __shared__ int tmp[256];
    int i = blockIdx.x * 256 + threadIdx.x;
    int v = (i < n) ? cnt[i] : 0;
    tmp[threadIdx.x] = v;
    __syncthreads();
    for (int off = 1; off < 256; off <<= 1) {
        int add = (threadIdx.x >= (unsigned)off) ? tmp[threadIdx.x - off] : 0;
        __syncthreads();
        tmp[threadIdx.x] += add;
        __syncthreads();
    }
    if (i < n) rp[i + 1] = tmp[threadIdx.x];
    if (threadIdx.x == 255) bsum[blockIdx.x] = tmp[255];
}
__global__ void scan2_k(int* __restrict__ bsum, int nb) {
    __shared__ int tmp[1024];
    int v = ((int)threadIdx.x < nb) ? bsum[threadIdx.x] : 0;
    tmp[threadIdx.x] = v;
    __syncthreads();
    for (int off = 1; off < 1024; off <<= 1) {
        int add = (threadIdx.x >= (unsigned)off) ? tmp[threadIdx.x - off] : 0;
        __syncthreads();
        tmp[threadIdx.x] += add;
        __syncthreads();
    }
    if ((int)threadIdx.x < nb) bsum[threadIdx.x] = tmp[threadIdx.x] - v; // exclusive
}
__global__ void scan3_k(int* __restrict__ rp, const int* __restrict__ bsum, int n) {
    int i = blockIdx.x * 256 + threadIdx.x;
    if (i < n) rp[i + 1] += bsum[blockIdx.x];
    if (i == 0) rp[0] = 0;
}

__global__ void fill_k(const int* __restrict__ src, const int* __restrict__ dst,
                       const int* __restrict__ rp, int* __restrict__ cursor,
                       int* __restrict__ srcs, int E) {
    int e = blockIdx.x * blockDim.x + threadIdx.x;
    if (e < E) {
        int d = dst[e];
        int p = atomicAdd(&cursor[d], 1);
        srcs[rp[d] + p] = src[e];
    }
}

// ---------- f32 -> bf16 feature conversion (4 elems/thread) ----------
__global__ void cvt_k(const float* __restrict__ x, unsigned short* __restrict__ xb, int n4) {
    int i = blockIdx.x * 256 + threadIdx.x;
    if (i < n4) {
        float4 v = ((const float4*)x)[i];
        unsigned long long o = (unsigned long long)f2b(v.x)
                             | ((unsigned long long)f2b(v.y) << 16)
                             | ((unsigned long long)f2b(v.z) << 32)
                             | ((unsigned long long)f2b(v.w) << 48);
        ((unsigned long long*)xb)[i] = o;
    }
}

// ---------- weight repack: Bp[((k>>3)*128 + n)*8 + (k&7)] = bf16(W[n][k]) ----------
__global__ void packw_k(const float* __restrict__ W, unsigned short* __restrict__ Bp) {
    int i = blockIdx.x * 256 + threadIdx.x;   // 16384 elems
    int n = i >> 7, k = i & 127;
    Bp[(((k >> 3) * FD) + n) * 8 + (k & 7)] = f2b(W[n * FD + k]);
}

// ---------- aggregation: one wave per node, bf16 gather, f32 accumulate ----------
__global__ __launch_bounds__(256) void aggb_k(const unsigned short* __restrict__ hb,
                                              const int* __restrict__ rp,
                                              const int* __restrict__ srcs,
                                              unsigned short* __restrict__ aggb, int N) {
    int wid = threadIdx.x >> 6, lane = threadIdx.x & 63;
    int node = blockIdx.x * 4 + wid;
    if (node >= N) return;
    int e0 = rp[node], e1 = rp[node + 1];
    float a0 = 0.f, a1 = 0.f;
    int e = e0;
    for (; e + 1 < e1; e += 2) {
        int s0 = srcs[e], s1 = srcs[e + 1];
        unsigned u0 = ((const unsigned*)(hb + (size_t)s0 * FD))[lane];
        unsigned u1 = ((const unsigned*)(hb + (size_t)s1 * FD))[lane];
        a0 += b2f((unsigned short)(u0 & 0xFFFF)) + b2f((unsigned short)(u1 & 0xFFFF));
        a1 += b2f((unsigned short)(u0 >> 16))    + b2f((unsigned short)(u1 >> 16));
    }
    if (e < e1) {
        int s0 = srcs[e];
        unsigned u0 = ((const unsigned*)(hb + (size_t)s0 * FD))[lane];
        a0 += b2f((unsigned short)(u0 & 0xFFFF));
        a1 += b2f((unsigned short)(u0 >> 16));
    }
    unsigned o = (unsigned)f2b(a0) | ((unsigned)f2b(a1) << 16);
    ((unsigned*)(aggb + (size_t)node * FD))[lane] = o;
}

// ---------- MFMA GEMM: out[m][n] = sum_k [agg|hin][m][k] * [Wrel;Wroot]T[k][n] + b ----------
// block: 256 thr = 4 waves; tile 64 nodes x 128 cols; wave owns 32-col strip, all 64 rows.
template <int OUT_BF16>
__global__ __launch_bounds__(256) void mgemm_k(
        const unsigned short* __restrict__ aggb, const unsigned short* __restrict__ hin,
        const unsigned short* __restrict__ BpRel, const unsigned short* __restrict__ BpRoot,
        const float* __restrict__ bias, void* __restrict__ outp, int N, int relu) {
    int wid = threadIdx.x >> 6, lane = threadIdx.x & 63;
    int l15 = lane & 15, lhi = lane >> 4;
    int b0 = blockIdx.x * 64;
    int n0 = wid * 32;

    f32x4 acc[4][2];
#pragma unroll
    for (int r = 0; r < 4; ++r)
#pragma unroll
        for (int t = 0; t < 2; ++t) acc[r][t] = (f32x4){0.f, 0.f, 0.f, 0.f};

#pragma unroll
    for (int half = 0; half < 2; ++half) {
        const unsigned short* F  = half ? hin : aggb;
        const unsigned short* Bp = half ? BpRoot : BpRel;
#pragma unroll
        for (int kk = 0; kk < 4; ++kk) {
            short8 bf0 = *(const short8*)(Bp + (((kk * 4 + lhi) * FD) + n0 + l15) * 8);
            short8 bf1 = *(const short8*)(Bp + (((kk * 4 + lhi) * FD) + n0 + 16 + l15) * 8);
#pragma unroll
            for (int r = 0; r < 4; ++r) {
                int row = b0 + r * 16 + l15;
                if (row >= N) row = N - 1;
                short8 af = *(const short8*)(F + (size_t)row * FD + kk * 32 + lhi * 8);
                acc[r][0] = __builtin_amdgcn_mfma_f32_16x16x32_bf16(af, bf0, acc[r][0], 0, 0, 0);
                acc[r][1] = __builtin_amdgcn_mfma_f32_16x16x32_bf16(af, bf1, acc[r][1], 0, 0, 0);
            }
        }
    }

    float bb0 = bias[n0 + l15];
    float bb1 = bias[n0 + 16 + l15];
#pragma unroll
    for (int r = 0; r < 4; ++r) {
#pragma unroll
        for (int t = 0; t < 2; ++t) {
            int col = n0 + t * 16 + l15;
            float bb = t ? bb1 : bb0;
#pragma unroll
            for (int j = 0; j < 4; ++j) {
                int row = b0 + r * 16 + lhi * 4 + j;
                if (row < N) {
                    float v = acc[r][t][j] + bb;
                    if (relu) v = fmaxf(v, 0.f);
                    if (OUT_BF16)
                        ((unsigned short*)outp)[(size_t)row * FD + col] = f2b(v);
                    else
                        ((float*)outp)[(size_t)row * FD + col] = v;
                }
            }
        }
    }
}

extern "C" void kernel_launch(void* const* d_in, const int* in_sizes, int n_in,
                              void* d_out, int out_size, void* d_ws, size_t ws_size,
                              hipStream_t stream) {
    const float* x   = (const float*)d_in[0];
    const int*   ei32 = (const int*)d_in[1];
    const long long* ei64 = (const long long*)d_in[1];
    const float* W1r = (const float*)d_in[2];
    const float* b1  = (const float*)d_in[3];
    const float* W1o = (const float*)d_in[4];
    const float* W2r = (const float*)d_in[5];
    const float* b2  = (const float*)d_in[6];
    const float* W2o = (const float*)d_in[7];
    const float* W3r = (const float*)d_in[8];
    const float* b3  = (const float*)d_in[9];
    const float* W3o = (const float*)d_in[10];

    int N = in_sizes[0] / FD;
    int E = in_sizes[1] / 2;

    char* ws = (char*)d_ws;
    size_t off = 0;
    auto alloc = [&](size_t bytes) -> void* {
        void* p = ws + off;
        off = (off + bytes + 255) & ~(size_t)255;
        return p;
    };
    int* flag = (int*)alloc(4);
    int* rp   = (int*)alloc((size_t)(N + 1) * 4);
    int* cnt  = (int*)alloc((size_t)N * 4);
    int* cur  = (int*)alloc((size_t)N * 4);
    int* bsum = (int*)alloc(1024 * 4);
    int* s32  = (int*)alloc((size_t)E * 4);
    int* d32  = (int*)alloc((size_t)E * 4);
    int* srcs = (int*)alloc((size_t)E * 4);
    unsigned short* xb   = (unsigned short*)alloc((size_t)N * FD * 2);
    unsigned short* hb1  = (unsigned short*)alloc((size_t)N * FD * 2);
    unsigned short* hb2  = (unsigned short*)alloc((size_t)N * FD * 2);
    unsigned short* aggb = (unsigned short*)alloc((size_t)N * FD * 2);
    unsigned short* Wp[6];
    for (int i = 0; i < 6; ++i) Wp[i] = (unsigned short*)alloc((size_t)FD * FD * 2);
    (void)ws_size; (void)n_in; (void)out_size;

    hipMemsetAsync(cnt, 0, (size_t)N * 4, stream);
    hipMemsetAsync(cur, 0, (size_t)N * 4, stream);

    detect_k<<<1, 256, 0, stream>>>((const unsigned int*)d_in[1], flag, E);
    convert_k<<<(E + 255) / 256, 256, 0, stream>>>(ei32, ei64, flag, s32, d32, E);
    count_k<<<(E + 255) / 256, 256, 0, stream>>>(d32, cnt, E);
    int nb = (N + 255) / 256;
    scan1_k<<<nb, 256, 0, stream>>>(cnt, rp, bsum, N);
    scan2_k<<<1, 1024, 0, stream>>>(bsum, nb);
    scan3_k<<<nb, 256, 0, stream>>>(rp, bsum, N);
    fill_k<<<(E + 255) / 256, 256, 0, stream>>>(s32, d32, rp, cur, srcs, E);

    cvt_k<<<(N * FD / 4 + 255) / 256, 256, 0, stream>>>(x, xb, N * FD / 4);
    packw_k<<<64, 256, 0, stream>>>(W1r, Wp[0]);
    packw_k<<<64, 256, 0, stream>>>(W1o, Wp[1]);
    packw_k<<<64, 256, 0, stream>>>(W2r, Wp[2]);
    packw_k<<<64, 256, 0, stream>>>(W2o, Wp[3]);
    packw_k<<<64, 256, 0, stream>>>(W3r, Wp[4]);
    packw_k<<<64, 256, 0, stream>>>(W3o, Wp[5]);

    int ablocks = (N + 3) / 4;
    int gblocks = (N + 63) / 64;

    aggb_k<<<ablocks, 256, 0, stream>>>(xb, rp, srcs, aggb, N);
    mgemm_k<1><<<gblocks, 256, 0, stream>>>(aggb, xb, Wp[0], Wp[1], b1, hb1, N, 1);

    aggb_k<<<ablocks, 256, 0, stream>>>(hb1, rp, srcs, aggb, N);
    mgemm_k<1><<<gblocks, 256, 0, stream>>>(aggb, hb1, Wp[2], Wp[3], b2, hb2, N, 1);

    aggb_k<<<ablocks, 256, 0, stream>>>(hb2, rp, srcs, aggb, N);
    mgemm_k<0><<<gblocks, 256, 0, stream>>>(aggb, hb2, Wp[4], Wp[5], b3, d_out, N, 0);
}

// Round 3
// 237.810 us; speedup vs baseline: 3.1414x; 1.4085x over previous
//
#include <hip/hip_runtime.h>

#define FD 128
typedef __attribute__((ext_vector_type(8))) short short8;
typedef __attribute__((ext_vector_type(4))) float f32x4;

static __device__ __forceinline__ unsigned short f2b(float f) {
    unsigned u = __builtin_bit_cast(unsigned, f);
    unsigned r = (u + 0x7FFFu + ((u >> 16) & 1u)) >> 16;
    return (unsigned short)r;
}
static __device__ __forceinline__ float b2f(unsigned short h) {
    unsigned u = ((unsigned)h) << 16;
    return __builtin_bit_cast(float, u);
}

// edge accessors handling either int32 or int64 storage of (2,E) edge_index
static __device__ __forceinline__ int edgeDst(const void* ei, int e, int E, int i32) {
    return i32 ? ((const int*)ei)[E + e] : (int)((const long long*)ei)[E + e];
}
static __device__ __forceinline__ int2 edgePair(const void* ei, int e, int E, int i32) {
    if (i32) { const int* p = (const int*)ei; return make_int2(p[e], p[E + e]); }
    const long long* p = (const long long*)ei;
    return make_int2((int)p[e], (int)p[E + e]);
}

// ---------- edge-index dtype detection ----------
__global__ void detect_k(const unsigned int* __restrict__ ei, int* __restrict__ flag, int nelem) {
    __shared__ int any;
    if (threadIdx.x == 0) any = 0;
    __syncthreads();
    int samples = 2048;
    if (samples > nelem) samples = nelem;
    for (int i = threadIdx.x; i < samples; i += blockDim.x)
        if (ei[2 * i + 1] != 0u) any = 1;
    __syncthreads();
    if (threadIdx.x == 0) *flag = any;   // any!=0 -> int32 data
}

// ---------- bucket histogram (bucket = dst >> 8) ----------
__global__ __launch_bounds__(256) void hist_k(const void* __restrict__ ei,
                                              const int* __restrict__ flag,
                                              int* __restrict__ bucketCnt, int E) {
    __shared__ int h[256];
    h[threadIdx.x] = 0;
    __syncthreads();
    int i32 = *flag;
    int base = blockIdx.x * 2048;
#pragma unroll
    for (int i = 0; i < 8; ++i) {
        int e = base + i * 256 + threadIdx.x;
        if (e < E) atomicAdd(&h[edgeDst(ei, e, E, i32) >> 8], 1);
    }
    __syncthreads();
    if (h[threadIdx.x]) atomicAdd(&bucketCnt[threadIdx.x], h[threadIdx.x]);
}

// ---------- scan bucket counts -> bb (bucket starts), init gcur, set rp[N] ----------
__global__ __launch_bounds__(256) void scanbb_k(const int* __restrict__ bucketCnt,
                                                int* __restrict__ bb, int* __restrict__ gcur,
                                                int* __restrict__ rp, int NB, int N, int E) {
    __shared__ int tmp[256];
    int t = threadIdx.x;
    int v = (t < NB) ? bucketCnt[t] : 0;
    tmp[t] = v;
    __syncthreads();
    for (int off = 1; off < 256; off <<= 1) {
        int add = (t >= off) ? tmp[t - off] : 0;
        __syncthreads();
        tmp[t] += add;
        __syncthreads();
    }
    int excl = tmp[t] - v;
    bb[t] = excl;
    gcur[t] = excl;
    if (t == 255) bb[256] = tmp[255];
    if (t == NB - 1) bb[NB] = tmp[t];
    if (t == 0) rp[N] = E;
}

// ---------- bin edges into bucket regions (block-local dense segments) ----------
__global__ __launch_bounds__(512) void bin_k(const void* __restrict__ ei,
                                             const int* __restrict__ flag,
                                             int* __restrict__ gcur,
                                             int2* __restrict__ binned, int E) {
    __shared__ int h[256];
    __shared__ int gb[256];
    __shared__ int lc[256];
    int t = threadIdx.x;
    if (t < 256) { h[t] = 0; lc[t] = 0; }
    __syncthreads();
    int i32 = *flag;
    int base = blockIdx.x * 8192;
#pragma unroll
    for (int i = 0; i < 16; ++i) {
        int e = base + i * 512 + t;
        if (e < E) atomicAdd(&h[edgeDst(ei, e, E, i32) >> 8], 1);
    }
    __syncthreads();
    if (t < 256 && h[t]) gb[t] = atomicAdd(&gcur[t], h[t]);
    __syncthreads();
#pragma unroll
    for (int i = 0; i < 16; ++i) {
        int e = base + i * 512 + t;
        if (e < E) {
            int2 p = edgePair(ei, e, E, i32);
            int b = p.y >> 8;
            int r = atomicAdd(&lc[b], 1);
            binned[gb[b] + r] = p;
        }
    }
}

// ---------- per-bucket CSR: rp + srcs, all writes block-local & dense ----------
__global__ __launch_bounds__(256) void csr_k(const int2* __restrict__ binned,
                                             const int* __restrict__ bb,
                                             int* __restrict__ rp, int* __restrict__ srcs, int N) {
    __shared__ int h[256];
    __shared__ int cur[256];
    int t = threadIdx.x;
    int b = blockIdx.x;
    int base = bb[b], end = bb[b + 1];
    int n0 = b << 8;
    h[t] = 0;
    __syncthreads();
    for (int i = base + t; i < end; i += 256)
        atomicAdd(&h[binned[i].y - n0], 1);
    __syncthreads();
    int v = h[t];
    for (int off = 1; off < 256; off <<= 1) {
        int add = (t >= off) ? h[t - off] : 0;
        __syncthreads();
        h[t] += add;
        __syncthreads();
    }
    int excl = h[t] - v;   // exclusive scan value for node n0+t
    int n = n0 + t;
    if (n < N) rp[n] = base + excl;
    cur[t] = base + excl;
    __syncthreads();
    for (int i = base + t; i < end; i += 256) {
        int2 p = binned[i];
        int pos = atomicAdd(&cur[p.y - n0], 1);
        srcs[pos] = p.x;
    }
}

// ---------- f32 -> bf16 feature conversion ----------
__global__ void cvt_k(const float* __restrict__ x, unsigned short* __restrict__ xb, int n4) {
    int i = blockIdx.x * 256 + threadIdx.x;
    if (i < n4) {
        float4 v = ((const float4*)x)[i];
        unsigned long long o = (unsigned long long)f2b(v.x)
                             | ((unsigned long long)f2b(v.y) << 16)
                             | ((unsigned long long)f2b(v.z) << 32)
                             | ((unsigned long long)f2b(v.w) << 48);
        ((unsigned long long*)xb)[i] = o;
    }
}

// ---------- weight repack: Bp[((k>>3)*128 + n)*8 + (k&7)] = bf16(W[n][k]) ----------
__global__ void packw_k(const float* __restrict__ W, unsigned short* __restrict__ Bp) {
    int i = blockIdx.x * 256 + threadIdx.x;   // 16384 elems
    int n = i >> 7, k = i & 127;
    Bp[(((k >> 3) * FD) + n) * 8 + (k & 7)] = f2b(W[n * FD + k]);
}

// ---------- aggregation: one wave per node, dwordx4 gathers (4 rows/wave/instr) ----------
__global__ __launch_bounds__(256) void aggb_k(const unsigned short* __restrict__ hb,
                                              const int* __restrict__ rp,
                                              const int* __restrict__ srcs,
                                              unsigned short* __restrict__ aggb, int N) {
    int wid = threadIdx.x >> 6, lane = threadIdx.x & 63;
    int node = blockIdx.x * 4 + wid;
    if (node >= N) return;
    int g = lane >> 4, c = lane & 15;
    int e0 = rp[node], e1 = rp[node + 1];
    float a[8];
#pragma unroll
    for (int j = 0; j < 8; ++j) a[j] = 0.f;
    for (int idx = e0 + g; idx < e1; idx += 4) {
        int s = srcs[idx];
        uint4 v = *(const uint4*)(hb + (size_t)s * FD + c * 8);
        a[0] += b2f((unsigned short)(v.x & 0xFFFF));
        a[1] += b2f((unsigned short)(v.x >> 16));
        a[2] += b2f((unsigned short)(v.y & 0xFFFF));
        a[3] += b2f((unsigned short)(v.y >> 16));
        a[4] += b2f((unsigned short)(v.z & 0xFFFF));
        a[5] += b2f((unsigned short)(v.z >> 16));
        a[6] += b2f((unsigned short)(v.w & 0xFFFF));
        a[7] += b2f((unsigned short)(v.w >> 16));
    }
#pragma unroll
    for (int j = 0; j < 8; ++j) {
        a[j] += __shfl_xor(a[j], 16);
        a[j] += __shfl_xor(a[j], 32);
    }
    if (lane < 16) {
        uint4 o;
        o.x = (unsigned)f2b(a[0]) | ((unsigned)f2b(a[1]) << 16);
        o.y = (unsigned)f2b(a[2]) | ((unsigned)f2b(a[3]) << 16);
        o.z = (unsigned)f2b(a[4]) | ((unsigned)f2b(a[5]) << 16);
        o.w = (unsigned)f2b(a[6]) | ((unsigned)f2b(a[7]) << 16);
        *(uint4*)(aggb + (size_t)node * FD + c * 8) = o;
    }
}

// ---------- MFMA GEMM: out = [agg|hin] @ [Wrel;Wroot]^T + b ----------
template <int OUT_BF16>
__global__ __launch_bounds__(256) void mgemm_k(
        const unsigned short* __restrict__ aggb, const unsigned short* __restrict__ hin,
        const unsigned short* __restrict__ BpRel, const unsigned short* __restrict__ BpRoot,
        const float* __restrict__ bias, void* __restrict__ outp, int N, int relu) {
    int wid = threadIdx.x >> 6, lane = threadIdx.x & 63;
    int l15 = lane & 15, lhi = lane >> 4;
    int b0 = blockIdx.x * 64;
    int n0 = wid * 32;

    f32x4 acc[4][2];
#pragma unroll
    for (int r = 0; r < 4; ++r)
#pragma unroll
        for (int t = 0; t < 2; ++t) acc[r][t] = (f32x4){0.f, 0.f, 0.f, 0.f};

#pragma unroll
    for (int half = 0; half < 2; ++half) {
        const unsigned short* F  = half ? hin : aggb;
        const unsigned short* Bp = half ? BpRoot : BpRel;
#pragma unroll
        for (int kk = 0; kk < 4; ++kk) {
            short8 bf0 = *(const short8*)(Bp + (((kk * 4 + lhi) * FD) + n0 + l15) * 8);
            short8 bf1 = *(const short8*)(Bp + (((kk * 4 + lhi) * FD) + n0 + 16 + l15) * 8);
#pragma unroll
            for (int r = 0; r < 4; ++r) {
                int row = b0 + r * 16 + l15;
                if (row >= N) row = N - 1;
                short8 af = *(const short8*)(F + (size_t)row * FD + kk * 32 + lhi * 8);
                acc[r][0] = __builtin_amdgcn_mfma_f32_16x16x32_bf16(af, bf0, acc[r][0], 0, 0, 0);
                acc[r][1] = __builtin_amdgcn_mfma_f32_16x16x32_bf16(af, bf1, acc[r][1], 0, 0, 0);
            }
        }
    }

    float bb0 = bias[n0 + l15];
    float bb1 = bias[n0 + 16 + l15];
#pragma unroll
    for (int r = 0; r < 4; ++r) {
#pragma unroll
        for (int t = 0; t < 2; ++t) {
            int col = n0 + t * 16 + l15;
            float bb = t ? bb1 : bb0;
#pragma unroll
            for (int j = 0; j < 4; ++j) {
                int row = b0 + r * 16 + lhi * 4 + j;
                if (row < N) {
                    float v = acc[r][t][j] + bb;
                    if (relu) v = fmaxf(v, 0.f);
                    if (OUT_BF16)
                        ((unsigned short*)outp)[(size_t)row * FD + col] = f2b(v);
                    else
                        ((float*)outp)[(size_t)row * FD + col] = v;
                }
            }
        }
    }
}

extern "C" void kernel_launch(void* const* d_in, const int* in_sizes, int n_in,
                              void* d_out, int out_size, void* d_ws, size_t ws_size,
                              hipStream_t stream) {
    const float* x   = (const float*)d_in[0];
    const float* W1r = (const float*)d_in[2];
    const float* b1  = (const float*)d_in[3];
    const float* W1o = (const float*)d_in[4];
    const float* W2r = (const float*)d_in[5];
    const float* b2  = (const float*)d_in[6];
    const float* W2o = (const float*)d_in[7];
    const float* W3r = (const float*)d_in[8];
    const float* b3  = (const float*)d_in[9];
    const float* W3o = (const float*)d_in[10];

    int N = in_sizes[0] / FD;
    int E = in_sizes[1] / 2;
    int NB = (N + 255) >> 8;   // buckets of 256 nodes

    char* ws = (char*)d_ws;
    size_t off = 0;
    auto alloc = [&](size_t bytes) -> void* {
        void* p = ws + off;
        off = (off + bytes + 255) & ~(size_t)255;
        return p;
    };
    int*  flag      = (int*)alloc(4);
    int*  bucketCnt = (int*)alloc(256 * 4);
    int*  bb        = (int*)alloc(257 * 4);
    int*  gcur      = (int*)alloc(256 * 4);
    int*  rp        = (int*)alloc((size_t)(N + 1) * 4);
    int*  srcs      = (int*)alloc((size_t)E * 4);
    int2* binned    = (int2*)alloc((size_t)E * 8);
    unsigned short* xb   = (unsigned short*)alloc((size_t)N * FD * 2);
    unsigned short* hb1  = (unsigned short*)alloc((size_t)N * FD * 2);
    unsigned short* hb2  = (unsigned short*)alloc((size_t)N * FD * 2);
    unsigned short* aggb = (unsigned short*)alloc((size_t)N * FD * 2);
    unsigned short* Wp[6];
    for (int i = 0; i < 6; ++i) Wp[i] = (unsigned short*)alloc((size_t)FD * FD * 2);
    (void)ws_size; (void)n_in; (void)out_size;

    hipMemsetAsync(bucketCnt, 0, 256 * 4, stream);

    detect_k<<<1, 256, 0, stream>>>((const unsigned int*)d_in[1], flag, E);
    hist_k<<<(E + 2047) / 2048, 256, 0, stream>>>(d_in[1], flag, bucketCnt, E);
    scanbb_k<<<1, 256, 0, stream>>>(bucketCnt, bb, gcur, rp, NB, N, E);
    bin_k<<<(E + 8191) / 8192, 512, 0, stream>>>(d_in[1], flag, gcur, binned, E);
    csr_k<<<NB, 256, 0, stream>>>(binned, bb, rp, srcs, N);

    cvt_k<<<(N * FD / 4 + 255) / 256, 256, 0, stream>>>(x, xb, N * FD / 4);
    packw_k<<<64, 256, 0, stream>>>(W1r, Wp[0]);
    packw_k<<<64, 256, 0, stream>>>(W1o, Wp[1]);
    packw_k<<<64, 256, 0, stream>>>(W2r, Wp[2]);
    packw_k<<<64, 256, 0, stream>>>(W2o, Wp[3]);
    packw_k<<<64, 256, 0, stream>>>(W3r, Wp[4]);
    packw_k<<<64, 256, 0, stream>>>(W3o, Wp[5]);

    int ablocks = (N + 3) / 4;
    int gblocks = (N + 63) / 64;

    aggb_k<<<ablocks, 256, 0, stream>>>(xb, rp, srcs, aggb, N);
    mgemm_k<1><<<gblocks, 256, 0, stream>>>(aggb, xb, Wp[0], Wp[1], b1, hb1, N, 1);

    aggb_k<<<ablocks, 256, 0, stream>>>(hb1, rp, srcs, aggb, N);
    mgemm_k<1><<<gblocks, 256, 0, stream>>>(aggb, hb1, Wp[2], Wp[3], b2, hb2, N, 1);

    aggb_k<<<ablocks, 256, 0, stream>>>(hb2, rp, srcs, aggb, N);
    mgemm_k<0><<<gblocks, 256, 0, stream>>>(aggb, hb2, Wp[4], Wp[5], b3, d_out, N, 0);
}

// Round 4
// 211.855 us; speedup vs baseline: 3.5263x; 1.1225x over previous
//
#include <hip/hip_runtime.h>

#define FD 128
typedef __attribute__((ext_vector_type(8))) short short8;
typedef __attribute__((ext_vector_type(4))) float f32x4;

static __device__ __forceinline__ unsigned short f2b(float f) {
    unsigned u = __builtin_bit_cast(unsigned, f);
    unsigned r = (u + 0x7FFFu + ((u >> 16) & 1u)) >> 16;
    return (unsigned short)r;
}
static __device__ __forceinline__ float b2f(unsigned short h) {
    unsigned u = ((unsigned)h) << 16;
    return __builtin_bit_cast(float, u);
}

// edge accessors handling either int32 or int64 storage of (2,E) edge_index.
// int64 values fit in 32 bits -> load only the low word.
static __device__ __forceinline__ int edgeDst(const void* ei, int e, int E, int i32) {
    if (i32) return ((const int*)ei)[E + e];
    return ((const int*)ei)[2 * (E + e)];      // low word of little-endian int64
}
static __device__ __forceinline__ int2 edgePair(const void* ei, int e, int E, int i32) {
    if (i32) { const int* p = (const int*)ei; return make_int2(p[e], p[E + e]); }
    const int* p = (const int*)ei;
    return make_int2(p[2 * e], p[2 * (E + e)]);
}

// ---------- edge-index dtype detection + bucketCnt zeroing ----------
__global__ void detect_k(const unsigned int* __restrict__ ei, int* __restrict__ flag,
                         int* __restrict__ bucketCnt, int nelem) {
    bucketCnt[threadIdx.x] = 0;
    __shared__ int any;
    if (threadIdx.x == 0) any = 0;
    __syncthreads();
    int samples = 2048;
    if (samples > nelem) samples = nelem;
    for (int i = threadIdx.x; i < samples; i += blockDim.x)
        if (ei[2 * i + 1] != 0u) any = 1;
    __syncthreads();
    if (threadIdx.x == 0) *flag = any;   // any!=0 -> int32 data
}

// ---------- bucket histogram (bucket = dst >> 8) ----------
__global__ __launch_bounds__(256) void hist_k(const void* __restrict__ ei,
                                              const int* __restrict__ flag,
                                              int* __restrict__ bucketCnt, int E) {
    __shared__ int h[256];
    h[threadIdx.x] = 0;
    __syncthreads();
    int i32 = *flag;
    int base = blockIdx.x * 2048;
#pragma unroll
    for (int i = 0; i < 8; ++i) {
        int e = base + i * 256 + threadIdx.x;
        if (e < E) atomicAdd(&h[edgeDst(ei, e, E, i32) >> 8], 1);
    }
    __syncthreads();
    if (h[threadIdx.x]) atomicAdd(&bucketCnt[threadIdx.x], h[threadIdx.x]);
}

// ---------- scan bucket counts -> bb (bucket starts), init gcur, set rp[N] ----------
__global__ __launch_bounds__(256) void scanbb_k(const int* __restrict__ bucketCnt,
                                                int* __restrict__ bb, int* __restrict__ gcur,
                                                int* __restrict__ rp, int NB, int N, int E) {
    __shared__ int tmp[256];
    int t = threadIdx.x;
    int v = (t < NB) ? bucketCnt[t] : 0;
    tmp[t] = v;
    __syncthreads();
    for (int off = 1; off < 256; off <<= 1) {
        int add = (t >= off) ? tmp[t - off] : 0;
        __syncthreads();
        tmp[t] += add;
        __syncthreads();
    }
    int excl = tmp[t] - v;
    bb[t] = excl;
    gcur[t] = excl;
    if (t == 255) bb[256] = tmp[255];
    if (t == NB - 1) bb[NB] = tmp[t];
    if (t == 0) rp[N] = E;
}

// ---------- bin edges into bucket regions (block-local dense segments) ----------
__global__ __launch_bounds__(512) void bin_k(const void* __restrict__ ei,
                                             const int* __restrict__ flag,
                                             int* __restrict__ gcur,
                                             int2* __restrict__ binned, int E) {
    __shared__ int h[256];
    __shared__ int gb[256];
    __shared__ int lc[256];
    int t = threadIdx.x;
    if (t < 256) { h[t] = 0; lc[t] = 0; }
    __syncthreads();
    int i32 = *flag;
    int base = blockIdx.x * 8192;
#pragma unroll
    for (int i = 0; i < 16; ++i) {
        int e = base + i * 512 + t;
        if (e < E) atomicAdd(&h[edgeDst(ei, e, E, i32) >> 8], 1);
    }
    __syncthreads();
    if (t < 256 && h[t]) gb[t] = atomicAdd(&gcur[t], h[t]);
    __syncthreads();
#pragma unroll
    for (int i = 0; i < 16; ++i) {
        int e = base + i * 512 + t;
        if (e < E) {
            int2 p = edgePair(ei, e, E, i32);
            int b = p.y >> 8;
            int r = atomicAdd(&lc[b], 1);
            binned[gb[b] + r] = p;
        }
    }
}

// ---------- per-bucket CSR: rp + srcs, all writes block-local & dense ----------
__global__ __launch_bounds__(256) void csr_k(const int2* __restrict__ binned,
                                             const int* __restrict__ bb,
                                             int* __restrict__ rp, int* __restrict__ srcs, int N) {
    __shared__ int h[256];
    __shared__ int cur[256];
    int t = threadIdx.x;
    int b = blockIdx.x;
    int base = bb[b], end = bb[b + 1];
    int n0 = b << 8;
    h[t] = 0;
    __syncthreads();
    for (int i = base + t; i < end; i += 256)
        atomicAdd(&h[binned[i].y - n0], 1);
    __syncthreads();
    int v = h[t];
    for (int off = 1; off < 256; off <<= 1) {
        int add = (t >= off) ? h[t - off] : 0;
        __syncthreads();
        h[t] += add;
        __syncthreads();
    }
    int excl = h[t] - v;   // exclusive scan value for node n0+t
    int n = n0 + t;
    if (n < N) rp[n] = base + excl;
    cur[t] = base + excl;
    __syncthreads();
    for (int i = base + t; i < end; i += 256) {
        int2 p = binned[i];
        int pos = atomicAdd(&cur[p.y - n0], 1);
        srcs[pos] = p.x;
    }
}

// ---------- f32 -> bf16 feature conversion ----------
__global__ void cvt_k(const float* __restrict__ x, unsigned short* __restrict__ xb, int n4) {
    int i = blockIdx.x * 256 + threadIdx.x;
    if (i < n4) {
        float4 v = ((const float4*)x)[i];
        unsigned long long o = (unsigned long long)f2b(v.x)
                             | ((unsigned long long)f2b(v.y) << 16)
                             | ((unsigned long long)f2b(v.z) << 32)
                             | ((unsigned long long)f2b(v.w) << 48);
        ((unsigned long long*)xb)[i] = o;
    }
}

// ---------- weight repack (all 6): Bp[((k>>3)*128 + n)*8 + (k&7)] = bf16(W[n][k]) ----------
__global__ void packall_k(const float* __restrict__ Wa, const float* __restrict__ Wb,
                          const float* __restrict__ Wc, const float* __restrict__ Wd,
                          const float* __restrict__ We, const float* __restrict__ Wf,
                          unsigned short* __restrict__ P0, int stride) {
    int which = blockIdx.x >> 6;
    const float* W = which == 0 ? Wa : which == 1 ? Wb : which == 2 ? Wc
                   : which == 3 ? Wd : which == 4 ? We : Wf;
    unsigned short* P = P0 + (size_t)which * stride;
    int i = (blockIdx.x & 63) * 256 + threadIdx.x;
    int n = i >> 7, k = i & 127;
    P[(((k >> 3) * FD) + n) * 8 + (k & 7)] = f2b(W[n * FD + k]);
}

// ---------- aggregation: one wave per node, dwordx4 gathers, 8 edges in flight ----------
__global__ __launch_bounds__(256) void aggb_k(const unsigned short* __restrict__ hb,
                                              const int* __restrict__ rp,
                                              const int* __restrict__ srcs,
                                              unsigned short* __restrict__ aggb, int N) {
    int wid = threadIdx.x >> 6, lane = threadIdx.x & 63;
    int node = blockIdx.x * 4 + wid;
    if (node >= N) return;
    int g = lane >> 4, c = lane & 15;
    const unsigned short* hbc = hb + c * 8;
    int e0 = rp[node], e1 = rp[node + 1];
    float a[8];
#pragma unroll
    for (int j = 0; j < 8; ++j) a[j] = 0.f;
    int idx = e0 + g;
    for (; idx + 4 < e1; idx += 8) {
        int s0 = srcs[idx];
        int s1 = srcs[idx + 4];
        uint4 v0 = *(const uint4*)(hbc + (size_t)s0 * FD);
        uint4 v1 = *(const uint4*)(hbc + (size_t)s1 * FD);
        a[0] += b2f((unsigned short)(v0.x & 0xFFFF)) + b2f((unsigned short)(v1.x & 0xFFFF));
        a[1] += b2f((unsigned short)(v0.x >> 16))    + b2f((unsigned short)(v1.x >> 16));
        a[2] += b2f((unsigned short)(v0.y & 0xFFFF)) + b2f((unsigned short)(v1.y & 0xFFFF));
        a[3] += b2f((unsigned short)(v0.y >> 16))    + b2f((unsigned short)(v1.y >> 16));
        a[4] += b2f((unsigned short)(v0.z & 0xFFFF)) + b2f((unsigned short)(v1.z & 0xFFFF));
        a[5] += b2f((unsigned short)(v0.z >> 16))    + b2f((unsigned short)(v1.z >> 16));
        a[6] += b2f((unsigned short)(v0.w & 0xFFFF)) + b2f((unsigned short)(v1.w & 0xFFFF));
        a[7] += b2f((unsigned short)(v0.w >> 16))    + b2f((unsigned short)(v1.w >> 16));
    }
    if (idx < e1) {
        int s0 = srcs[idx];
        uint4 v0 = *(const uint4*)(hbc + (size_t)s0 * FD);
        a[0] += b2f((unsigned short)(v0.x & 0xFFFF));
        a[1] += b2f((unsigned short)(v0.x >> 16));
        a[2] += b2f((unsigned short)(v0.y & 0xFFFF));
        a[3] += b2f((unsigned short)(v0.y >> 16));
        a[4] += b2f((unsigned short)(v0.z & 0xFFFF));
        a[5] += b2f((unsigned short)(v0.z >> 16));
        a[6] += b2f((unsigned short)(v0.w & 0xFFFF));
        a[7] += b2f((unsigned short)(v0.w >> 16));
    }
#pragma unroll
    for (int j = 0; j < 8; ++j) {
        a[j] += __shfl_xor(a[j], 16);
        a[j] += __shfl_xor(a[j], 32);
    }
    if (lane < 16) {
        uint4 o;
        o.x = (unsigned)f2b(a[0]) | ((unsigned)f2b(a[1]) << 16);
        o.y = (unsigned)f2b(a[2]) | ((unsigned)f2b(a[3]) << 16);
        o.z = (unsigned)f2b(a[4]) | ((unsigned)f2b(a[5]) << 16);
        o.w = (unsigned)f2b(a[6]) | ((unsigned)f2b(a[7]) << 16);
        *(uint4*)(aggb + (size_t)node * FD + c * 8) = o;
    }
}

// ---------- MFMA GEMM: out = [agg|hin] @ [Wrel;Wroot]^T + b ----------
template <int OUT_BF16>
__global__ __launch_bounds__(256) void mgemm_k(
        const unsigned short* __restrict__ aggb, const unsigned short* __restrict__ hin,
        const unsigned short* __restrict__ BpRel, const unsigned short* __restrict__ BpRoot,
        const float* __restrict__ bias, void* __restrict__ outp, int N, int relu) {
    int wid = threadIdx.x >> 6, lane = threadIdx.x & 63;
    int l15 = lane & 15, lhi = lane >> 4;
    int b0 = blockIdx.x * 64;
    int n0 = wid * 32;

    f32x4 acc[4][2];
#pragma unroll
    for (int r = 0; r < 4; ++r)
#pragma unroll
        for (int t = 0; t < 2; ++t) acc[r][t] = (f32x4){0.f, 0.f, 0.f, 0.f};

#pragma unroll
    for (int half = 0; half < 2; ++half) {
        const unsigned short* F  = half ? hin : aggb;
        const unsigned short* Bp = half ? BpRoot : BpRel;
#pragma unroll
        for (int kk = 0; kk < 4; ++kk) {
            short8 bf0 = *(const short8*)(Bp + (((kk * 4 + lhi) * FD) + n0 + l15) * 8);
            short8 bf1 = *(const short8*)(Bp + (((kk * 4 + lhi) * FD) + n0 + 16 + l15) * 8);
#pragma unroll
            for (int r = 0; r < 4; ++r) {
                int row = b0 + r * 16 + l15;
                if (row >= N) row = N - 1;
                short8 af = *(const short8*)(F + (size_t)row * FD + kk * 32 + lhi * 8);
                acc[r][0] = __builtin_amdgcn_mfma_f32_16x16x32_bf16(af, bf0, acc[r][0], 0, 0, 0);
                acc[r][1] = __builtin_amdgcn_mfma_f32_16x16x32_bf16(af, bf1, acc[r][1], 0, 0, 0);
            }
        }
    }

    float bb0 = bias[n0 + l15];
    float bb1 = bias[n0 + 16 + l15];
#pragma unroll
    for (int r = 0; r < 4; ++r) {
#pragma unroll
        for (int t = 0; t < 2; ++t) {
            int col = n0 + t * 16 + l15;
            float bb = t ? bb1 : bb0;
#pragma unroll
            for (int j = 0; j < 4; ++j) {
                int row = b0 + r * 16 + lhi * 4 + j;
                if (row < N) {
                    float v = acc[r][t][j] + bb;
                    if (relu) v = fmaxf(v, 0.f);
                    if (OUT_BF16)
                        ((unsigned short*)outp)[(size_t)row * FD + col] = f2b(v);
                    else
                        ((float*)outp)[(size_t)row * FD + col] = v;
                }
            }
        }
    }
}

extern "C" void kernel_launch(void* const* d_in, const int* in_sizes, int n_in,
                              void* d_out, int out_size, void* d_ws, size_t ws_size,
                              hipStream_t stream) {
    const float* x   = (const float*)d_in[0];
    const float* W1r = (const float*)d_in[2];
    const float* b1  = (const float*)d_in[3];
    const float* W1o = (const float*)d_in[4];
    const float* W2r = (const float*)d_in[5];
    const float* b2  = (const float*)d_in[6];
    const float* W2o = (const float*)d_in[7];
    const float* W3r = (const float*)d_in[8];
    const float* b3  = (const float*)d_in[9];
    const float* W3o = (const float*)d_in[10];

    int N = in_sizes[0] / FD;
    int E = in_sizes[1] / 2;
    int NB = (N + 255) >> 8;   // buckets of 256 nodes

    char* ws = (char*)d_ws;
    size_t off = 0;
    auto alloc = [&](size_t bytes) -> void* {
        void* p = ws + off;
        off = (off + bytes + 255) & ~(size_t)255;
        return p;
    };
    int*  flag      = (int*)alloc(4);
    int*  bucketCnt = (int*)alloc(256 * 4);
    int*  bb        = (int*)alloc(257 * 4);
    int*  gcur      = (int*)alloc(256 * 4);
    int*  rp        = (int*)alloc((size_t)(N + 1) * 4);
    int*  srcs      = (int*)alloc((size_t)E * 4);
    int2* binned    = (int2*)alloc((size_t)E * 8);
    unsigned short* xb   = (unsigned short*)alloc((size_t)N * FD * 2);
    unsigned short* hb1  = (unsigned short*)alloc((size_t)N * FD * 2);
    unsigned short* hb2  = (unsigned short*)alloc((size_t)N * FD * 2);
    unsigned short* aggb = (unsigned short*)alloc((size_t)N * FD * 2);
    unsigned short* Wp   = (unsigned short*)alloc((size_t)6 * FD * FD * 2);
    (void)ws_size; (void)n_in; (void)out_size;

    detect_k<<<1, 256, 0, stream>>>((const unsigned int*)d_in[1], flag, bucketCnt, E);
    hist_k<<<(E + 2047) / 2048, 256, 0, stream>>>(d_in[1], flag, bucketCnt, E);
    scanbb_k<<<1, 256, 0, stream>>>(bucketCnt, bb, gcur, rp, NB, N, E);
    bin_k<<<(E + 8191) / 8192, 512, 0, stream>>>(d_in[1], flag, gcur, binned, E);
    csr_k<<<NB, 256, 0, stream>>>(binned, bb, rp, srcs, N);

    cvt_k<<<(N * FD / 4 + 255) / 256, 256, 0, stream>>>(x, xb, N * FD / 4);
    packall_k<<<6 * 64, 256, 0, stream>>>(W1r, W1o, W2r, W2o, W3r, W3o, Wp, FD * FD);

    const int stride = FD * FD;
    int ablocks = (N + 3) / 4;
    int gblocks = (N + 63) / 64;

    aggb_k<<<ablocks, 256, 0, stream>>>(xb, rp, srcs, aggb, N);
    mgemm_k<1><<<gblocks, 256, 0, stream>>>(aggb, xb, Wp + 0 * stride, Wp + 1 * stride, b1, hb1, N, 1);

    aggb_k<<<ablocks, 256, 0, stream>>>(hb1, rp, srcs, aggb, N);
    mgemm_k<1><<<gblocks, 256, 0, stream>>>(aggb, hb1, Wp + 2 * stride, Wp + 3 * stride, b2, hb2, N, 1);

    aggb_k<<<ablocks, 256, 0, stream>>>(hb2, rp, srcs, aggb, N);
    mgemm_k<0><<<gblocks, 256, 0, stream>>>(aggb, hb2, Wp + 4 * stride, Wp + 5 * stride, b3, d_out, N, 0);
}